// Round 8
// baseline (414.040 us; speedup 1.0000x reference)
//
#include <hip/hip_runtime.h>
#include <hip/hip_bf16.h>

#define N_NODES 100000
#define N_EDGES 1600000
#define IN_DIM 128
#define HID_DIM 256
#define OUT_DIM 128
#define NB ((N_NODES + 1023) / 1024)  // 98 scan blocks
#define DCHUNK 12500                  // legacy: N_NODES / 8 dst-range per XCD-group
#define EGRID 8192                    // legacy edge kernels
#define CAP 64                        // fixed-slot CSR capacity (P[deg>63] ~ 1e-13)
#define FFGRID 782                    // 782*256 = 200192 threads >= 200000 (8 edges/thread)
#define NSTRIP (N_NODES / 16)         // 6250 exact
#define GWAVES 2048                   // 512 blocks x 4 waves

// prologue fused-grid block ranges (E32 section removed in R7: fill reads ei directly)
#define PB_ZERO 391                   // cnt zero: 391*256 >= 100000
#define PB_PREP 258                   // weight prep: 66048 >= 65920
#define PB_CONVX 12500                // x->bf16: 3.2M float4 / 256
#define PB_TOTAL (PB_ZERO + PB_PREP + PB_CONVX)  // 13149

typedef __attribute__((ext_vector_type(8))) short bf16x8;
typedef __attribute__((ext_vector_type(4))) float f32x4;
typedef __attribute__((ext_vector_type(4))) float float4v;
typedef unsigned long long ull;
typedef unsigned short u16;

__device__ __forceinline__ float bf2f(u16 u) {
  union { unsigned int i; float f; } c; c.i = ((unsigned int)u) << 16; return c.f;
}
__device__ __forceinline__ u16 f2bf(float f) {
  __hip_bfloat16 h = __float2bfloat16(f);
  return *(u16*)&h;
}

// flags[0] = emode (1 = edge_index int64), flags[1] = fmode (1 = floats fp32).
__global__ void detect_kernel(const int* __restrict__ ei,
                              const unsigned int* __restrict__ xw,
                              int* __restrict__ flags) {
  int lane = threadIdx.x;  // blockDim = 64
  const long long* p = (const long long*)ei;
  long long v = p[lane & 15];
  int ebad = (lane < 16) && (v < 0 || v >= N_NODES);
  ull ebm = __ballot(ebad);
  int isf32 = 0;
  #pragma unroll
  for (int i = 0; i < 4; ++i) {
    unsigned int ex = (xw[lane * 4 + i] >> 7) & 0xFF;
    if (ex >= 0xC0) isf32 = 1;  // |v| >= 2^65: impossible for real data
  }
  ull fbm = __ballot(isf32);
  if (lane == 0) {
    flags[0] = (ebm == 0) ? 1 : 0;
    flags[1] = (fbm != 0) ? 1 : 0;
  }
}

__device__ __forceinline__ int edge_at(const int* ei, int idx, int mode) {
  return mode ? (int)((const long long*)ei)[idx] : ei[idx];
}

// Fused prologue: zero cnt | weight prep (transpose + bf16) | x -> bf16.
__global__ void prologue_kernel(const void* __restrict__ x,
                                const void* __restrict__ W1, const void* __restrict__ b1,
                                const void* __restrict__ W2, const void* __restrict__ b2,
                                const int* __restrict__ flags,
                                int* __restrict__ cnt,
                                u16* __restrict__ Wt1, u16* __restrict__ Wt2,
                                u16* __restrict__ b1c, u16* __restrict__ b2c,
                                u16* __restrict__ xc) {
  int b = blockIdx.x, tid = threadIdx.x;
  if (b < PB_ZERO) {
    int i = b * 256 + tid;
    if (i < N_NODES) cnt[i] = 0;
  } else if (b < PB_ZERO + PB_PREP) {
    int i = (b - PB_ZERO) * 256 + tid;
    int f = flags[1];
    auto cvt = [&](const void* P, int idx) -> u16 {
      return f ? f2bf(((const float*)P)[idx]) : ((const u16*)P)[idx];
    };
    if (i < 32768) {                     // W1: [128][256] -> Wt1 [256][128]
      int k = i >> 8, n = i & 255;
      Wt1[n * 128 + k] = cvt(W1, i);
    } else if (i < 65536) {              // W2: [256][128] -> Wt2 [128][256]
      int j = i - 32768;
      int k = j >> 7, n = j & 127;
      Wt2[n * 256 + k] = cvt(W2, j);
    } else if (i < 65792) {
      b1c[i - 65536] = cvt(b1, i - 65536);
    } else if (i < 65920) {
      b2c[i - 65792] = cvt(b2, i - 65792);
    }
  } else {
    int i = (b - PB_ZERO - PB_PREP) * 256 + tid;  // n4 = 3200000
    if (i >= N_NODES * IN_DIM / 4) return;
    if (flags[1]) {
      float4v v = ((const float4v*)x)[i];
      ull w = (ull)f2bf(v.x) | ((ull)f2bf(v.y) << 16) | ((ull)f2bf(v.z) << 32) |
              ((ull)f2bf(v.w) << 48);
      ((ull*)xc)[i] = w;
    } else {
      ((ull*)xc)[i] = ((const ull*)x)[i];
    }
  }
}

// Fixed-slot CSR scatter, unsliced + unconditional (R7).
// R6 failed because the XCD-slice predicate forced 8 sequential exec-mask
// blocks; compiler allocated 12 VGPR and re-serialized the chains (~2
// outstanding). Now: read ei ONCE (int64 or int32 mode), 8 edges/thread, phase
// 1 = 8 UNCONDITIONAL independent atomicAdds into p8[], phase 2 = 8 guarded
// stores. Cross-XCD atomics are device-scope-correct; edge list read replay
// (8x) and the prologue e32 conversion pass are both eliminated.
__global__ void fill_fixed_kernel(const int* __restrict__ ei,
                                  const int* __restrict__ flags,
                                  int* __restrict__ cnt, int* __restrict__ csrf) {
  int tg = blockIdx.x * 256 + threadIdx.x;
  int base = tg * 8;
  if (base >= N_EDGES) return;  // N_EDGES % 8 == 0: all 8 in-bounds
  int dv[8], sv[8];
  if (flags[0]) {               // int64 [2][E]: 64B per 8 edges, 16B-aligned
    const longlong2* ps = (const longlong2*)ei + (base >> 1);
    const longlong2* pd = (const longlong2*)ei + ((N_EDGES + base) >> 1);
    #pragma unroll
    for (int k = 0; k < 4; ++k) {
      longlong2 s2 = ps[k], d2 = pd[k];
      sv[2 * k] = (int)s2.x; sv[2 * k + 1] = (int)s2.y;
      dv[2 * k] = (int)d2.x; dv[2 * k + 1] = (int)d2.y;
    }
  } else {                      // int32 [2][E]
    int4 s0 = *(const int4*)(ei + base);
    int4 s1 = *(const int4*)(ei + base + 4);
    int4 d0 = *(const int4*)(ei + N_EDGES + base);
    int4 d1 = *(const int4*)(ei + N_EDGES + base + 4);
    sv[0] = s0.x; sv[1] = s0.y; sv[2] = s0.z; sv[3] = s0.w;
    sv[4] = s1.x; sv[5] = s1.y; sv[6] = s1.z; sv[7] = s1.w;
    dv[0] = d0.x; dv[1] = d0.y; dv[2] = d0.z; dv[3] = d0.w;
    dv[4] = d1.x; dv[5] = d1.y; dv[6] = d1.z; dv[7] = d1.w;
  }
  int p8[8];
  #pragma unroll
  for (int k = 0; k < 8; ++k) p8[k] = atomicAdd(&cnt[dv[k]], 1);  // 8 in flight
  #pragma unroll
  for (int k = 0; k < 8; ++k)
    if (p8[k] < CAP) csrf[dv[k] * CAP + p8[k]] = sv[k];  // drop-on-overflow; never OOB
}

// dinv from final cnt.
__global__ void degnorm_kernel(const int* __restrict__ cnt, float* __restrict__ dinv) {
  int i = blockIdx.x * 256 + threadIdx.x;
  if (i < N_NODES) dinv[i] = rsqrtf((float)(cnt[i] + 1));  // +1 self-loop
}

// ---- legacy exact-CSR path (fallback when ws too small; never taken on this
// harness — proven R6/R7). Reads ei directly via edge_at. ----
__global__ void count_kernel(const int* __restrict__ ei, const int* __restrict__ flags,
                             int* __restrict__ deg) {
  int g = blockIdx.x & 7;
  unsigned lo = (unsigned)(g * DCHUNK);
  unsigned hi = lo + DCHUNK; if (hi > N_NODES) hi = N_NODES;
  int m = flags[0];
  int stride = (EGRID >> 3) * 256;
  for (int e = (blockIdx.x >> 3) * 256 + threadIdx.x; e < N_EDGES; e += stride) {
    unsigned d = (unsigned)edge_at(ei, N_EDGES + e, m);
    if (d >= lo && d < hi) atomicAdd(&deg[d], 1);
  }
}

__global__ void zero_kernel(int* p, int n) {
  int i = blockIdx.x * 256 + threadIdx.x;
  if (i < n) p[i] = 0;
}

__global__ __launch_bounds__(1024) void bsum_kernel(const int* __restrict__ deg,
                                                    int* __restrict__ bsum, int n) {
  __shared__ int ws[16];
  int tid = threadIdx.x, lane = tid & 63, wid = tid >> 6;
  int idx = blockIdx.x * 1024 + tid;
  int v = (idx < n) ? deg[idx] : 0;
  #pragma unroll
  for (int o = 32; o > 0; o >>= 1) v += __shfl_down(v, o);
  if (lane == 0) ws[wid] = v;
  __syncthreads();
  if (tid == 0) {
    int r = 0;
    #pragma unroll
    for (int i = 0; i < 16; ++i) r += ws[i];
    bsum[blockIdx.x] = r;
  }
}

__global__ void bscan_kernel(const int* __restrict__ bsum, int* __restrict__ boff,
                             int* __restrict__ total, int nb) {
  int lane = threadIdx.x;  // blockDim = 64
  int carry = 0;
  for (int c = 0; c < (nb + 63) / 64; ++c) {
    int idx = c * 64 + lane;
    int v = (idx < nb) ? bsum[idx] : 0;
    int x = v;
    #pragma unroll
    for (int o = 1; o < 64; o <<= 1) {
      int y = __shfl_up(x, o);
      if (lane >= o) x += y;
    }
    if (idx < nb) boff[idx] = carry + x - v;
    carry += __shfl(x, 63);
  }
  if (lane == 0) *total = carry;
}

__global__ __launch_bounds__(1024) void bfill_kernel(const int* __restrict__ deg,
                                                     const int* __restrict__ boff,
                                                     int* __restrict__ off,
                                                     int* __restrict__ cur,
                                                     float* __restrict__ dinv, int n) {
  __shared__ int wsum[16];
  __shared__ int wpre[16];
  int tid = threadIdx.x, lane = tid & 63, wid = tid >> 6;
  int idx = blockIdx.x * 1024 + tid;
  int v = (idx < n) ? deg[idx] : 0;
  int x = v;
  #pragma unroll
  for (int o = 1; o < 64; o <<= 1) {
    int y = __shfl_up(x, o);
    if (lane >= o) x += y;
  }
  if (lane == 63) wsum[wid] = x;
  __syncthreads();
  if (tid == 0) {
    int r = 0;
    #pragma unroll
    for (int i = 0; i < 16; ++i) { wpre[i] = r; r += wsum[i]; }
  }
  __syncthreads();
  int excl = boff[blockIdx.x] + wpre[wid] + x - v;
  if (idx < n) {
    off[idx] = excl;
    cur[idx] = excl;
    dinv[idx] = rsqrtf((float)(v + 1));  // +1 self-loop
  }
}

__global__ void fill_kernel(const int* __restrict__ ei, const int* __restrict__ flags,
                            int* __restrict__ cur, int* __restrict__ csr) {
  int g = blockIdx.x & 7;
  unsigned lo = (unsigned)(g * DCHUNK);
  unsigned hi = lo + DCHUNK; if (hi > N_NODES) hi = N_NODES;
  int m = flags[0];
  int stride = (EGRID >> 3) * 256;
  for (int e = (blockIdx.x >> 3) * 256 + threadIdx.x; e < N_EDGES; e += stride) {
    unsigned d = (unsigned)edge_at(ei, N_EDGES + e, m);
    if (d >= lo && d < hi) {
      int s = edge_at(ei, e, m);
      int p = atomicAdd(&cur[d], 1);
      if ((unsigned)p < N_EDGES) csr[p] = s;
    }
  }
}

// One wave per node; 4x16-lane edge-parallel groups, 16B/lane row gathers.
// FIXED: edge range is [du*CAP, du*CAP + min(cnt[du],CAP)) from the slot table.
template <bool BIAS, bool OUTF32, bool FIXED>
__global__ __launch_bounds__(256) void agg_kernel(
    const u16* __restrict__ V, const int* __restrict__ off,
    const int* __restrict__ csr, const float* __restrict__ dinv,
    const u16* __restrict__ bias, void* __restrict__ outv) {
  int d = (blockIdx.x * 256 + threadIdx.x) >> 6;
  int lane = threadIdx.x & 63;
  if (d >= N_NODES) return;
  int du = __builtin_amdgcn_readfirstlane(d);   // wave-uniform by construction
  int grp = lane >> 4, sub = lane & 15;
  float dv = dinv[du];
  // self-loop: broadcast 16B slice; only grp 0 keeps it (counted once in reduce)
  bf16x8 w0 = *(const bf16x8*)(V + (size_t)du * 128 + sub * 8);
  float self_s = (grp == 0) ? dv : 0.0f;
  float a[8];
  #pragma unroll
  for (int k = 0; k < 8; ++k) a[k] = self_s * bf2f((u16)w0[k]);
  int e, e1;
  if (FIXED) {
    int c = __builtin_amdgcn_readfirstlane(off[du]);  // off == cnt in fixed path
    if (c > CAP) c = CAP;
    e = du * CAP;
    e1 = e + c;
  } else {
    e  = __builtin_amdgcn_readfirstlane(off[du]);
    e1 = __builtin_amdgcn_readfirstlane(off[du + 1]);
  }
  // 8 edges per iteration: two independent 4-edge chains for load ILP
  for (; e + 8 <= e1; e += 8) {
    int sA = csr[e + grp];
    int sB = csr[e + 4 + grp];
    float dsA = dinv[sA];
    float dsB = dinv[sB];
    bf16x8 wA = *(const bf16x8*)(V + (size_t)sA * 128 + sub * 8);
    bf16x8 wB = *(const bf16x8*)(V + (size_t)sB * 128 + sub * 8);
    #pragma unroll
    for (int k = 0; k < 8; ++k) a[k] = fmaf(dsA, bf2f((u16)wA[k]), a[k]);
    #pragma unroll
    for (int k = 0; k < 8; ++k) a[k] = fmaf(dsB, bf2f((u16)wB[k]), a[k]);
  }
  for (; e + 4 <= e1; e += 4) {
    int s = csr[e + grp];
    float ds = dinv[s];
    bf16x8 w = *(const bf16x8*)(V + (size_t)s * 128 + sub * 8);
    #pragma unroll
    for (int k = 0; k < 8; ++k) a[k] = fmaf(ds, bf2f((u16)w[k]), a[k]);
  }
  int rem = e1 - e;  // 0..3 tail edges
  if (rem > 0) {
    int ee = e + (grp < rem ? grp : 0);       // clamped in-bounds (e < e1)
    int s = csr[ee];
    float ds = (grp < rem) ? dinv[s] : 0.0f;  // inactive groups contribute 0
    bf16x8 w = *(const bf16x8*)(V + (size_t)s * 128 + sub * 8);
    #pragma unroll
    for (int k = 0; k < 8; ++k) a[k] = fmaf(ds, bf2f((u16)w[k]), a[k]);
  }
  // reduce the 4 group-partials; then apply dst norm once
  #pragma unroll
  for (int k = 0; k < 8; ++k) {
    a[k] += __shfl_xor(a[k], 16);
    a[k] += __shfl_xor(a[k], 32);
    a[k] *= dv;
  }
  if (BIAS) {
    bf16x8 bv = *(const bf16x8*)(bias + sub * 8);
    #pragma unroll
    for (int k = 0; k < 8; ++k) a[k] += bf2f((u16)bv[k]);
  }
  if (OUTF32) {
    if (grp < 2) {
      f32x4 o4;
      #pragma unroll
      for (int r = 0; r < 4; ++r) o4[r] = a[grp * 4 + r];
      *(f32x4*)((float*)outv + (size_t)du * 128 + sub * 8 + grp * 4) = o4;
    }
  } else {
    if (grp == 0) {
      bf16x8 ob;
      #pragma unroll
      for (int k = 0; k < 8; ++k) ob[k] = (short)f2bf(a[k]);
      *(bf16x8*)((u16*)outv + (size_t)du * 128 + sub * 8) = ob;
    }
  }
}

// MLP layer 1: h = relu(xa @ W1 + b1). Wt1 (64 KB) in LDS, 16B-block XOR swizzle.
__global__ __launch_bounds__(256) void mlp1_kernel(
    const u16* __restrict__ xa, const u16* __restrict__ Wt1,
    const u16* __restrict__ b1, u16* __restrict__ h) {
  __shared__ u16 B[32768];  // 65536 B
  int tid = threadIdx.x;
  #pragma unroll
  for (int j = 0; j < 16; ++j) {
    int i = j * 256 + tid;                         // 16B-block index 0..4095
    int row = i >> 4, blk = i & 15;
    int phys = (row << 4) | (blk ^ (row & 15));
    *(bf16x8*)&B[phys * 8] = *(const bf16x8*)(Wt1 + (size_t)i * 8);
  }
  __syncthreads();
  int wid = tid >> 6, lane = tid & 63, ml = lane & 15, q = lane >> 4;
  for (int s = blockIdx.x * 4 + wid; s < NSTRIP; s += GWAVES) {
    const short* Ar = (const short*)xa + (size_t)(s * 16 + ml) * IN_DIM + q * 8;
    f32x4 acc[16] = {};
    #pragma unroll
    for (int k0 = 0; k0 < IN_DIM; k0 += 32) {
      bf16x8 a = *(const bf16x8*)(Ar + k0);
      int kb = k0 >> 3;
      #pragma unroll
      for (int t = 0; t < 16; ++t) {
        int brow = t * 16 + ml;                    // brow & 15 == ml
        const u16* Bp = &B[(((unsigned)brow << 4) | (unsigned)((kb + q) ^ ml)) * 8];
        acc[t] = __builtin_amdgcn_mfma_f32_16x16x32_bf16(a, *(const bf16x8*)Bp, acc[t], 0, 0, 0);
      }
    }
    size_t hb = (size_t)s * 16 * HID_DIM;
    #pragma unroll
    for (int t = 0; t < 16; ++t) {
      float bv = bf2f(b1[t * 16 + ml]);
      #pragma unroll
      for (int r = 0; r < 4; ++r)
        h[hb + (size_t)(q * 4 + r) * HID_DIM + t * 16 + ml] =
            f2bf(fmaxf(acc[t][r] + bv, 0.0f));
    }
  }
}

// MLP layer 2: xg = h @ W2 (bias added later in agg2). Wt2 (64 KB) in LDS.
__global__ __launch_bounds__(256) void mlp2_kernel(
    const u16* __restrict__ h, const u16* __restrict__ Wt2, u16* __restrict__ xg) {
  __shared__ u16 B[32768];  // 65536 B
  int tid = threadIdx.x;
  #pragma unroll
  for (int j = 0; j < 16; ++j) {
    int i = j * 256 + tid;                         // 16B-block index 0..4095
    int row = i >> 5, blk = i & 31;
    int phys = (row << 5) | (blk ^ (row & 15));
    *(bf16x8*)&B[phys * 8] = *(const bf16x8*)(Wt2 + (size_t)i * 8);
  }
  __syncthreads();
  int wid = tid >> 6, lane = tid & 63, ml = lane & 15, q = lane >> 4;
  for (int s = blockIdx.x * 4 + wid; s < NSTRIP; s += GWAVES) {
    const short* Ar = (const short*)h + (size_t)(s * 16 + ml) * HID_DIM + q * 8;
    f32x4 acc[8] = {};
    #pragma unroll
    for (int k0 = 0; k0 < HID_DIM; k0 += 32) {
      bf16x8 a = *(const bf16x8*)(Ar + k0);
      int kb = k0 >> 3;
      #pragma unroll
      for (int t = 0; t < 8; ++t) {
        int brow = t * 16 + ml;                    // brow & 15 == ml
        const u16* Bp = &B[(((unsigned)brow << 5) | (unsigned)((kb + q) ^ ml)) * 8];
        acc[t] = __builtin_amdgcn_mfma_f32_16x16x32_bf16(a, *(const bf16x8*)Bp, acc[t], 0, 0, 0);
      }
    }
    size_t gb = (size_t)s * 16 * OUT_DIM;
    #pragma unroll
    for (int t = 0; t < 8; ++t) {
      #pragma unroll
      for (int r = 0; r < 4; ++r)
        xg[gb + (size_t)(q * 4 + r) * OUT_DIM + t * 16 + ml] = f2bf(acc[t][r]);
    }
  }
}

extern "C" void kernel_launch(void* const* d_in, const int* in_sizes, int n_in,
                              void* d_out, int out_size, void* d_ws, size_t ws_size,
                              hipStream_t stream) {
  const void* x  = d_in[0];
  const int*  ei = (const int*)d_in[1];
  const void* W1 = d_in[2];
  const void* b1 = d_in[3];
  const void* W2 = d_in[4];
  const void* b2 = d_in[5];

  char* wsb = (char*)d_ws;

  // ---- fixed-slot layout (~77.7 MB); fall back to proven legacy if ws too small
  {
    size_t o = 0;
    auto carve = [&](size_t bytes) {
      o = (o + 511) & ~(size_t)511;
      void* p = wsb + o;
      o += bytes;
      return p;
    };
    int*   flags = (int*)carve(8);
    int*   cnt  = (int*)carve((size_t)N_NODES * 4);
    float* dinv = (float*)carve((size_t)N_NODES * 4);
    int*   csrf = (int*)carve((size_t)N_NODES * CAP * 4);      // 25.6 MB slot table
    u16*   Wt1 = (u16*)carve((size_t)IN_DIM * HID_DIM * 2);
    u16*   Wt2 = (u16*)carve((size_t)HID_DIM * OUT_DIM * 2);
    u16*   b1c = (u16*)carve((size_t)HID_DIM * 2);
    u16*   b2c = (u16*)carve((size_t)OUT_DIM * 2);
    u16*   xc  = (u16*)carve((size_t)N_NODES * 128 * 2);
    u16*   xa  = (u16*)carve((size_t)N_NODES * 128 * 2);
    u16*   h   = (u16*)d_out;
    if (o <= ws_size) {
      detect_kernel<<<1, 64, 0, stream>>>(ei, (const unsigned int*)x, flags);
      prologue_kernel<<<PB_TOTAL, 256, 0, stream>>>(x, W1, b1, W2, b2, flags,
                                                    cnt, Wt1, Wt2, b1c, b2c, xc);
      fill_fixed_kernel<<<FFGRID, 256, 0, stream>>>(ei, flags, cnt, csrf);
      degnorm_kernel<<<(N_NODES + 255) / 256, 256, 0, stream>>>(cnt, dinv);
      agg_kernel<false, false, true>
          <<<(N_NODES * 64) / 256, 256, 0, stream>>>(xc, cnt, csrf, dinv, nullptr, xa);
      mlp1_kernel<<<512, 256, 0, stream>>>(xa, Wt1, b1c, h);
      mlp2_kernel<<<512, 256, 0, stream>>>(h, Wt2, xa);
      agg_kernel<true, true, true>
          <<<(N_NODES * 64) / 256, 256, 0, stream>>>(xa, cnt, csrf, dinv, b2c, d_out);
      return;
    }
  }

  // ---- legacy exact-CSR pipeline (reads ei directly; never taken on this harness)
  size_t o = 0;
  auto carve = [&](size_t bytes) {
    o = (o + 511) & ~(size_t)511;
    void* p = wsb + o;
    o += bytes;
    return p;
  };
  int*   flags = (int*)carve(8);
  int*   deg  = (int*)carve((size_t)N_NODES * 4);
  int*   off  = (int*)carve((size_t)(N_NODES + 1) * 4);
  int*   cur  = (int*)carve((size_t)N_NODES * 4);
  float* dinv = (float*)carve((size_t)N_NODES * 4);
  int*   csr  = (int*)carve((size_t)N_EDGES * 4);
  int*   bsum = (int*)carve((size_t)NB * 4);
  int*   boff = (int*)carve((size_t)NB * 4);
  u16*   Wt1 = (u16*)carve((size_t)IN_DIM * HID_DIM * 2);
  u16*   Wt2 = (u16*)carve((size_t)HID_DIM * OUT_DIM * 2);
  u16*   b1c = (u16*)carve((size_t)HID_DIM * 2);
  u16*   b2c = (u16*)carve((size_t)OUT_DIM * 2);
  u16*   xc  = (u16*)carve((size_t)N_NODES * 128 * 2);
  u16*   xa  = (u16*)carve((size_t)N_NODES * 128 * 2);
  u16*   h   = (u16*)d_out;

  detect_kernel<<<1, 64, 0, stream>>>(ei, (const unsigned int*)x, flags);
  zero_kernel<<<(N_NODES + 255) / 256, 256, 0, stream>>>(deg, N_NODES);
  prologue_kernel<<<PB_TOTAL, 256, 0, stream>>>(x, W1, b1, W2, b2, flags,
                                                deg, Wt1, Wt2, b1c, b2c, xc);
  count_kernel<<<EGRID, 256, 0, stream>>>(ei, flags, deg);
  bsum_kernel<<<NB, 1024, 0, stream>>>(deg, bsum, N_NODES);
  bscan_kernel<<<1, 64, 0, stream>>>(bsum, boff, off + N_NODES, NB);
  bfill_kernel<<<NB, 1024, 0, stream>>>(deg, boff, off, cur, dinv, N_NODES);
  fill_kernel<<<EGRID, 256, 0, stream>>>(ei, flags, cur, csr);

  agg_kernel<false, false, false>
      <<<(N_NODES * 64) / 256, 256, 0, stream>>>(xc, off, csr, dinv, nullptr, xa);
  mlp1_kernel<<<512, 256, 0, stream>>>(xa, Wt1, b1c, h);
  mlp2_kernel<<<512, 256, 0, stream>>>(h, Wt2, xa);
  agg_kernel<true, true, false>
      <<<(N_NODES * 64) / 256, 256, 0, stream>>>(xa, off, csr, dinv, b2c, d_out);
}

// Round 9
// 349.519 us; speedup vs baseline: 1.1846x; 1.1846x over previous
//
#include <hip/hip_runtime.h>
#include <hip/hip_bf16.h>

#define N_NODES 100000
#define N_EDGES 1600000
#define IN_DIM 128
#define HID_DIM 256
#define OUT_DIM 128
#define NB ((N_NODES + 1023) / 1024)  // legacy scan blocks
#define DCHUNK 12500                  // N_NODES / 8 dst-range per XCD-group
#define EGRID 8192                    // legacy edge kernels
#define CAP 64                        // fixed-slot CSR capacity (P[deg>63] ~ 1e-13)
#define NSTRIP (N_NODES / 16)         // 6250 exact
#define GWAVES 2048                   // 512 blocks x 4 waves

// fused fill+prep kernel block ranges
#define FILLB 8192                    // sliced fill: 1024 slices x 8 XCD groups (proven 71us @76% occ)
#define FPREP 258                     // weight prep: 66048 >= 65920
#define FCONVX 12500                  // x->bf16: 3.2M float4 / 256
#define FUSED_TOTAL (FILLB + FPREP + FCONVX)  // 20950

// legacy prologue ranges
#define PB_ZERO 391
#define PB_PREP 258
#define PB_CONVX 12500
#define PB_TOTAL (PB_ZERO + PB_PREP + PB_CONVX)

typedef __attribute__((ext_vector_type(8))) short bf16x8;
typedef __attribute__((ext_vector_type(4))) float f32x4;
typedef __attribute__((ext_vector_type(4))) float float4v;
typedef unsigned long long ull;
typedef unsigned short u16;

__device__ __forceinline__ float bf2f(u16 u) {
  union { unsigned int i; float f; } c; c.i = ((unsigned int)u) << 16; return c.f;
}
__device__ __forceinline__ u16 f2bf(float f) {
  __hip_bfloat16 h = __float2bfloat16(f);
  return *(u16*)&h;
}

// Block 0 / wave 0: detect input modes. All blocks: zero cnt.
// flags[0] = emode (1 = edge_index int64), flags[1] = fmode (1 = floats fp32).
__global__ void detect_zero_kernel(const int* __restrict__ ei,
                                   const unsigned int* __restrict__ xw,
                                   int* __restrict__ flags, int* __restrict__ cnt) {
  int tid = threadIdx.x;
  int i = blockIdx.x * 256 + tid;
  if (i < N_NODES) cnt[i] = 0;
  if (blockIdx.x == 0 && tid < 64) {  // wave 0 exactly
    const long long* p = (const long long*)ei;
    long long v = p[tid & 15];
    int ebad = (tid < 16) && (v < 0 || v >= N_NODES);
    ull ebm = __ballot(ebad);
    int isf32 = 0;
    #pragma unroll
    for (int k = 0; k < 4; ++k) {
      unsigned int ex = (xw[tid * 4 + k] >> 7) & 0xFF;
      if (ex >= 0xC0) isf32 = 1;  // |v| >= 2^65: impossible for real data
    }
    ull fbm = __ballot(isf32);
    if (tid == 0) {
      flags[0] = (ebm == 0) ? 1 : 0;
      flags[1] = (fbm != 0) ? 1 : 0;
    }
  }
}

__device__ __forceinline__ int edge_at(const int* ei, int idx, int mode) {
  return mode ? (int)((const long long*)ei)[idx] : ei[idx];
}

// Fused fill + weight-prep + convx (R9).
// fill (blocks 0..FILLB-1): XCD dst-sliced grid-stride scatter — R5/R6/R8
// triangulated an L2 atomic-pipe wall (~1.2 atomic/cyc/XCD, ~70us for 1.6M
// sliced atomics; occupancy 40->76% changed nothing; unsliced cross-XCD
// atomics DOUBLED it). fill is therefore BW/VALU-idle: the prep+convx blocks
// (pure BW, ~15us serial) stream through freed CU slots under the atomic wall.
// Reads ei directly (no int32 conversion pass — R7's verified -12us kept).
__global__ void fill_prep_kernel(const int* __restrict__ ei, const void* __restrict__ x,
                                 const void* __restrict__ W1, const void* __restrict__ b1,
                                 const void* __restrict__ W2, const void* __restrict__ b2,
                                 const int* __restrict__ flags,
                                 int* __restrict__ cnt, int* __restrict__ csrf,
                                 u16* __restrict__ Wt1, u16* __restrict__ Wt2,
                                 u16* __restrict__ b1c, u16* __restrict__ b2c,
                                 u16* __restrict__ xc) {
  int b = blockIdx.x, tid = threadIdx.x;
  if (b < FILLB) {
    int g = b & 7;
    unsigned lo = (unsigned)(g * DCHUNK);
    unsigned hi = lo + DCHUNK; if (hi > N_NODES) hi = N_NODES;
    int stride = (FILLB >> 3) * 256;              // 262144
    int e0 = (b >> 3) * 256 + tid;
    if (flags[0]) {
      const long long* s64 = (const long long*)ei;
      const long long* d64 = s64 + N_EDGES;
      for (int e = e0; e < N_EDGES; e += stride) {
        unsigned d = (unsigned)(int)d64[e];
        if (d >= lo && d < hi) {
          int s = (int)s64[e];
          int p = atomicAdd(&cnt[d], 1);
          if (p < CAP) csrf[d * CAP + p] = s;     // drop-on-overflow; never OOB
        }
      }
    } else {
      const int* d32 = ei + N_EDGES;
      for (int e = e0; e < N_EDGES; e += stride) {
        unsigned d = (unsigned)d32[e];
        if (d >= lo && d < hi) {
          int s = ei[e];
          int p = atomicAdd(&cnt[d], 1);
          if (p < CAP) csrf[d * CAP + p] = s;
        }
      }
    }
  } else if (b < FILLB + FPREP) {
    int i = (b - FILLB) * 256 + tid;
    int f = flags[1];
    auto cvt = [&](const void* P, int idx) -> u16 {
      return f ? f2bf(((const float*)P)[idx]) : ((const u16*)P)[idx];
    };
    if (i < 32768) {                     // W1: [128][256] -> Wt1 [256][128]
      int k = i >> 8, n = i & 255;
      Wt1[n * 128 + k] = cvt(W1, i);
    } else if (i < 65536) {              // W2: [256][128] -> Wt2 [128][256]
      int j = i - 32768;
      int k = j >> 7, n = j & 127;
      Wt2[n * 256 + k] = cvt(W2, j);
    } else if (i < 65792) {
      b1c[i - 65536] = cvt(b1, i - 65536);
    } else if (i < 65920) {
      b2c[i - 65792] = cvt(b2, i - 65792);
    }
  } else {
    int i = (b - FILLB - FPREP) * 256 + tid;      // n4 = 3200000
    if (i >= N_NODES * IN_DIM / 4) return;
    if (flags[1]) {
      float4v v = ((const float4v*)x)[i];
      ull w = (ull)f2bf(v.x) | ((ull)f2bf(v.y) << 16) | ((ull)f2bf(v.z) << 32) |
              ((ull)f2bf(v.w) << 48);
      ((ull*)xc)[i] = w;
    } else {
      ((ull*)xc)[i] = ((const ull*)x)[i];
    }
  }
}

// dinv from final cnt.
__global__ void degnorm_kernel(const int* __restrict__ cnt, float* __restrict__ dinv) {
  int i = blockIdx.x * 256 + threadIdx.x;
  if (i < N_NODES) dinv[i] = rsqrtf((float)(cnt[i] + 1));  // +1 self-loop
}

// ---- legacy exact-CSR path (fallback when ws too small; never taken on this
// harness — fixed path proven R6-R8). ----
__global__ void zero_kernel(int* p, int n) {
  int i = blockIdx.x * 256 + threadIdx.x;
  if (i < n) p[i] = 0;
}

__global__ void prologue_kernel(const void* __restrict__ x,
                                const void* __restrict__ W1, const void* __restrict__ b1,
                                const void* __restrict__ W2, const void* __restrict__ b2,
                                const int* __restrict__ flags,
                                int* __restrict__ cnt,
                                u16* __restrict__ Wt1, u16* __restrict__ Wt2,
                                u16* __restrict__ b1c, u16* __restrict__ b2c,
                                u16* __restrict__ xc) {
  int b = blockIdx.x, tid = threadIdx.x;
  if (b < PB_ZERO) {
    int i = b * 256 + tid;
    if (i < N_NODES) cnt[i] = 0;
  } else if (b < PB_ZERO + PB_PREP) {
    int i = (b - PB_ZERO) * 256 + tid;
    int f = flags[1];
    auto cvt = [&](const void* P, int idx) -> u16 {
      return f ? f2bf(((const float*)P)[idx]) : ((const u16*)P)[idx];
    };
    if (i < 32768) {
      int k = i >> 8, n = i & 255;
      Wt1[n * 128 + k] = cvt(W1, i);
    } else if (i < 65536) {
      int j = i - 32768;
      int k = j >> 7, n = j & 127;
      Wt2[n * 256 + k] = cvt(W2, j);
    } else if (i < 65792) {
      b1c[i - 65536] = cvt(b1, i - 65536);
    } else if (i < 65920) {
      b2c[i - 65792] = cvt(b2, i - 65792);
    }
  } else {
    int i = (b - PB_ZERO - PB_PREP) * 256 + tid;
    if (i >= N_NODES * IN_DIM / 4) return;
    if (flags[1]) {
      float4v v = ((const float4v*)x)[i];
      ull w = (ull)f2bf(v.x) | ((ull)f2bf(v.y) << 16) | ((ull)f2bf(v.z) << 32) |
              ((ull)f2bf(v.w) << 48);
      ((ull*)xc)[i] = w;
    } else {
      ((ull*)xc)[i] = ((const ull*)x)[i];
    }
  }
}

__global__ void count_kernel(const int* __restrict__ ei, const int* __restrict__ flags,
                             int* __restrict__ deg) {
  int g = blockIdx.x & 7;
  unsigned lo = (unsigned)(g * DCHUNK);
  unsigned hi = lo + DCHUNK; if (hi > N_NODES) hi = N_NODES;
  int m = flags[0];
  int stride = (EGRID >> 3) * 256;
  for (int e = (blockIdx.x >> 3) * 256 + threadIdx.x; e < N_EDGES; e += stride) {
    unsigned d = (unsigned)edge_at(ei, N_EDGES + e, m);
    if (d >= lo && d < hi) atomicAdd(&deg[d], 1);
  }
}

__global__ __launch_bounds__(1024) void bsum_kernel(const int* __restrict__ deg,
                                                    int* __restrict__ bsum, int n) {
  __shared__ int ws[16];
  int tid = threadIdx.x, lane = tid & 63, wid = tid >> 6;
  int idx = blockIdx.x * 1024 + tid;
  int v = (idx < n) ? deg[idx] : 0;
  #pragma unroll
  for (int o = 32; o > 0; o >>= 1) v += __shfl_down(v, o);
  if (lane == 0) ws[wid] = v;
  __syncthreads();
  if (tid == 0) {
    int r = 0;
    #pragma unroll
    for (int i = 0; i < 16; ++i) r += ws[i];
    bsum[blockIdx.x] = r;
  }
}

__global__ void bscan_kernel(const int* __restrict__ bsum, int* __restrict__ boff,
                             int* __restrict__ total, int nb) {
  int lane = threadIdx.x;  // blockDim = 64
  int carry = 0;
  for (int c = 0; c < (nb + 63) / 64; ++c) {
    int idx = c * 64 + lane;
    int v = (idx < nb) ? bsum[idx] : 0;
    int x = v;
    #pragma unroll
    for (int o = 1; o < 64; o <<= 1) {
      int y = __shfl_up(x, o);
      if (lane >= o) x += y;
    }
    if (idx < nb) boff[idx] = carry + x - v;
    carry += __shfl(x, 63);
  }
  if (lane == 0) *total = carry;
}

__global__ __launch_bounds__(1024) void bfill_kernel(const int* __restrict__ deg,
                                                     const int* __restrict__ boff,
                                                     int* __restrict__ off,
                                                     int* __restrict__ cur,
                                                     float* __restrict__ dinv, int n) {
  __shared__ int wsum[16];
  __shared__ int wpre[16];
  int tid = threadIdx.x, lane = tid & 63, wid = tid >> 6;
  int idx = blockIdx.x * 1024 + tid;
  int v = (idx < n) ? deg[idx] : 0;
  int x = v;
  #pragma unroll
  for (int o = 1; o < 64; o <<= 1) {
    int y = __shfl_up(x, o);
    if (lane >= o) x += y;
  }
  if (lane == 63) wsum[wid] = x;
  __syncthreads();
  if (tid == 0) {
    int r = 0;
    #pragma unroll
    for (int i = 0; i < 16; ++i) { wpre[i] = r; r += wsum[i]; }
  }
  __syncthreads();
  int excl = boff[blockIdx.x] + wpre[wid] + x - v;
  if (idx < n) {
    off[idx] = excl;
    cur[idx] = excl;
    dinv[idx] = rsqrtf((float)(v + 1));
  }
}

__global__ void fill_kernel(const int* __restrict__ ei, const int* __restrict__ flags,
                            int* __restrict__ cur, int* __restrict__ csr) {
  int g = blockIdx.x & 7;
  unsigned lo = (unsigned)(g * DCHUNK);
  unsigned hi = lo + DCHUNK; if (hi > N_NODES) hi = N_NODES;
  int m = flags[0];
  int stride = (EGRID >> 3) * 256;
  for (int e = (blockIdx.x >> 3) * 256 + threadIdx.x; e < N_EDGES; e += stride) {
    unsigned d = (unsigned)edge_at(ei, N_EDGES + e, m);
    if (d >= lo && d < hi) {
      int s = edge_at(ei, e, m);
      int p = atomicAdd(&cur[d], 1);
      if ((unsigned)p < N_EDGES) csr[p] = s;
    }
  }
}

// One wave per node; 4x16-lane edge-parallel groups, 16B/lane row gathers.
// FIXED: edge range is [du*CAP, du*CAP + min(cnt[du],CAP)) from the slot table.
template <bool BIAS, bool OUTF32, bool FIXED>
__global__ __launch_bounds__(256) void agg_kernel(
    const u16* __restrict__ V, const int* __restrict__ off,
    const int* __restrict__ csr, const float* __restrict__ dinv,
    const u16* __restrict__ bias, void* __restrict__ outv) {
  int d = (blockIdx.x * 256 + threadIdx.x) >> 6;
  int lane = threadIdx.x & 63;
  if (d >= N_NODES) return;
  int du = __builtin_amdgcn_readfirstlane(d);   // wave-uniform by construction
  int grp = lane >> 4, sub = lane & 15;
  float dv = dinv[du];
  // self-loop: broadcast 16B slice; only grp 0 keeps it (counted once in reduce)
  bf16x8 w0 = *(const bf16x8*)(V + (size_t)du * 128 + sub * 8);
  float self_s = (grp == 0) ? dv : 0.0f;
  float a[8];
  #pragma unroll
  for (int k = 0; k < 8; ++k) a[k] = self_s * bf2f((u16)w0[k]);
  int e, e1;
  if (FIXED) {
    int c = __builtin_amdgcn_readfirstlane(off[du]);  // off == cnt in fixed path
    if (c > CAP) c = CAP;
    e = du * CAP;
    e1 = e + c;
  } else {
    e  = __builtin_amdgcn_readfirstlane(off[du]);
    e1 = __builtin_amdgcn_readfirstlane(off[du + 1]);
  }
  // 8 edges per iteration: two independent 4-edge chains for load ILP
  for (; e + 8 <= e1; e += 8) {
    int sA = csr[e + grp];
    int sB = csr[e + 4 + grp];
    float dsA = dinv[sA];
    float dsB = dinv[sB];
    bf16x8 wA = *(const bf16x8*)(V + (size_t)sA * 128 + sub * 8);
    bf16x8 wB = *(const bf16x8*)(V + (size_t)sB * 128 + sub * 8);
    #pragma unroll
    for (int k = 0; k < 8; ++k) a[k] = fmaf(dsA, bf2f((u16)wA[k]), a[k]);
    #pragma unroll
    for (int k = 0; k < 8; ++k) a[k] = fmaf(dsB, bf2f((u16)wB[k]), a[k]);
  }
  for (; e + 4 <= e1; e += 4) {
    int s = csr[e + grp];
    float ds = dinv[s];
    bf16x8 w = *(const bf16x8*)(V + (size_t)s * 128 + sub * 8);
    #pragma unroll
    for (int k = 0; k < 8; ++k) a[k] = fmaf(ds, bf2f((u16)w[k]), a[k]);
  }
  int rem = e1 - e;  // 0..3 tail edges
  if (rem > 0) {
    int ee = e + (grp < rem ? grp : 0);       // clamped in-bounds (e < e1)
    int s = csr[ee];
    float ds = (grp < rem) ? dinv[s] : 0.0f;  // inactive groups contribute 0
    bf16x8 w = *(const bf16x8*)(V + (size_t)s * 128 + sub * 8);
    #pragma unroll
    for (int k = 0; k < 8; ++k) a[k] = fmaf(ds, bf2f((u16)w[k]), a[k]);
  }
  // reduce the 4 group-partials; then apply dst norm once
  #pragma unroll
  for (int k = 0; k < 8; ++k) {
    a[k] += __shfl_xor(a[k], 16);
    a[k] += __shfl_xor(a[k], 32);
    a[k] *= dv;
  }
  if (BIAS) {
    bf16x8 bv = *(const bf16x8*)(bias + sub * 8);
    #pragma unroll
    for (int k = 0; k < 8; ++k) a[k] += bf2f((u16)bv[k]);
  }
  if (OUTF32) {
    if (grp < 2) {
      f32x4 o4;
      #pragma unroll
      for (int r = 0; r < 4; ++r) o4[r] = a[grp * 4 + r];
      *(f32x4*)((float*)outv + (size_t)du * 128 + sub * 8 + grp * 4) = o4;
    }
  } else {
    if (grp == 0) {
      bf16x8 ob;
      #pragma unroll
      for (int k = 0; k < 8; ++k) ob[k] = (short)f2bf(a[k]);
      *(bf16x8*)((u16*)outv + (size_t)du * 128 + sub * 8) = ob;
    }
  }
}

// MLP layer 1: h = relu(xa @ W1 + b1). Wt1 (64 KB) in LDS, 16B-block XOR swizzle.
__global__ __launch_bounds__(256) void mlp1_kernel(
    const u16* __restrict__ xa, const u16* __restrict__ Wt1,
    const u16* __restrict__ b1, u16* __restrict__ h) {
  __shared__ u16 B[32768];  // 65536 B
  int tid = threadIdx.x;
  #pragma unroll
  for (int j = 0; j < 16; ++j) {
    int i = j * 256 + tid;                         // 16B-block index 0..4095
    int row = i >> 4, blk = i & 15;
    int phys = (row << 4) | (blk ^ (row & 15));
    *(bf16x8*)&B[phys * 8] = *(const bf16x8*)(Wt1 + (size_t)i * 8);
  }
  __syncthreads();
  int wid = tid >> 6, lane = tid & 63, ml = lane & 15, q = lane >> 4;
  for (int s = blockIdx.x * 4 + wid; s < NSTRIP; s += GWAVES) {
    const short* Ar = (const short*)xa + (size_t)(s * 16 + ml) * IN_DIM + q * 8;
    f32x4 acc[16] = {};
    #pragma unroll
    for (int k0 = 0; k0 < IN_DIM; k0 += 32) {
      bf16x8 a = *(const bf16x8*)(Ar + k0);
      int kb = k0 >> 3;
      #pragma unroll
      for (int t = 0; t < 16; ++t) {
        int brow = t * 16 + ml;                    // brow & 15 == ml
        const u16* Bp = &B[(((unsigned)brow << 4) | (unsigned)((kb + q) ^ ml)) * 8];
        acc[t] = __builtin_amdgcn_mfma_f32_16x16x32_bf16(a, *(const bf16x8*)Bp, acc[t], 0, 0, 0);
      }
    }
    size_t hb = (size_t)s * 16 * HID_DIM;
    #pragma unroll
    for (int t = 0; t < 16; ++t) {
      float bv = bf2f(b1[t * 16 + ml]);
      #pragma unroll
      for (int r = 0; r < 4; ++r)
        h[hb + (size_t)(q * 4 + r) * HID_DIM + t * 16 + ml] =
            f2bf(fmaxf(acc[t][r] + bv, 0.0f));
    }
  }
}

// MLP layer 2: xg = h @ W2 (bias added later in agg2). Wt2 (64 KB) in LDS.
__global__ __launch_bounds__(256) void mlp2_kernel(
    const u16* __restrict__ h, const u16* __restrict__ Wt2, u16* __restrict__ xg) {
  __shared__ u16 B[32768];  // 65536 B
  int tid = threadIdx.x;
  #pragma unroll
  for (int j = 0; j < 16; ++j) {
    int i = j * 256 + tid;                         // 16B-block index 0..4095
    int row = i >> 5, blk = i & 31;
    int phys = (row << 5) | (blk ^ (row & 15));
    *(bf16x8*)&B[phys * 8] = *(const bf16x8*)(Wt2 + (size_t)i * 8);
  }
  __syncthreads();
  int wid = tid >> 6, lane = tid & 63, ml = lane & 15, q = lane >> 4;
  for (int s = blockIdx.x * 4 + wid; s < NSTRIP; s += GWAVES) {
    const short* Ar = (const short*)h + (size_t)(s * 16 + ml) * HID_DIM + q * 8;
    f32x4 acc[8] = {};
    #pragma unroll
    for (int k0 = 0; k0 < HID_DIM; k0 += 32) {
      bf16x8 a = *(const bf16x8*)(Ar + k0);
      int kb = k0 >> 3;
      #pragma unroll
      for (int t = 0; t < 8; ++t) {
        int brow = t * 16 + ml;                    // brow & 15 == ml
        const u16* Bp = &B[(((unsigned)brow << 5) | (unsigned)((kb + q) ^ ml)) * 8];
        acc[t] = __builtin_amdgcn_mfma_f32_16x16x32_bf16(a, *(const bf16x8*)Bp, acc[t], 0, 0, 0);
      }
    }
    size_t gb = (size_t)s * 16 * OUT_DIM;
    #pragma unroll
    for (int t = 0; t < 8; ++t) {
      #pragma unroll
      for (int r = 0; r < 4; ++r)
        xg[gb + (size_t)(q * 4 + r) * OUT_DIM + t * 16 + ml] = f2bf(acc[t][r]);
    }
  }
}

extern "C" void kernel_launch(void* const* d_in, const int* in_sizes, int n_in,
                              void* d_out, int out_size, void* d_ws, size_t ws_size,
                              hipStream_t stream) {
  const void* x  = d_in[0];
  const int*  ei = (const int*)d_in[1];
  const void* W1 = d_in[2];
  const void* b1 = d_in[3];
  const void* W2 = d_in[4];
  const void* b2 = d_in[5];

  char* wsb = (char*)d_ws;

  // ---- fixed-slot layout (~77.7 MB); fall back to proven legacy if ws too small
  {
    size_t o = 0;
    auto carve = [&](size_t bytes) {
      o = (o + 511) & ~(size_t)511;
      void* p = wsb + o;
      o += bytes;
      return p;
    };
    int*   flags = (int*)carve(8);
    int*   cnt  = (int*)carve((size_t)N_NODES * 4);
    float* dinv = (float*)carve((size_t)N_NODES * 4);
    int*   csrf = (int*)carve((size_t)N_NODES * CAP * 4);      // 25.6 MB slot table
    u16*   Wt1 = (u16*)carve((size_t)IN_DIM * HID_DIM * 2);
    u16*   Wt2 = (u16*)carve((size_t)HID_DIM * OUT_DIM * 2);
    u16*   b1c = (u16*)carve((size_t)HID_DIM * 2);
    u16*   b2c = (u16*)carve((size_t)OUT_DIM * 2);
    u16*   xc  = (u16*)carve((size_t)N_NODES * 128 * 2);
    u16*   xa  = (u16*)carve((size_t)N_NODES * 128 * 2);
    u16*   h   = (u16*)d_out;
    if (o <= ws_size) {
      detect_zero_kernel<<<391, 256, 0, stream>>>(ei, (const unsigned int*)x, flags, cnt);
      fill_prep_kernel<<<FUSED_TOTAL, 256, 0, stream>>>(ei, x, W1, b1, W2, b2, flags,
                                                        cnt, csrf, Wt1, Wt2, b1c, b2c, xc);
      degnorm_kernel<<<(N_NODES + 255) / 256, 256, 0, stream>>>(cnt, dinv);
      agg_kernel<false, false, true>
          <<<(N_NODES * 64) / 256, 256, 0, stream>>>(xc, cnt, csrf, dinv, nullptr, xa);
      mlp1_kernel<<<512, 256, 0, stream>>>(xa, Wt1, b1c, h);
      mlp2_kernel<<<512, 256, 0, stream>>>(h, Wt2, xa);
      agg_kernel<true, true, true>
          <<<(N_NODES * 64) / 256, 256, 0, stream>>>(xa, cnt, csrf, dinv, b2c, d_out);
      return;
    }
  }

  // ---- legacy exact-CSR pipeline (reads ei directly; never taken on this harness)
  size_t o = 0;
  auto carve = [&](size_t bytes) {
    o = (o + 511) & ~(size_t)511;
    void* p = wsb + o;
    o += bytes;
    return p;
  };
  int*   flags = (int*)carve(8);
  int*   deg  = (int*)carve((size_t)N_NODES * 4);
  int*   off  = (int*)carve((size_t)(N_NODES + 1) * 4);
  int*   cur  = (int*)carve((size_t)N_NODES * 4);
  float* dinv = (float*)carve((size_t)N_NODES * 4);
  int*   csr  = (int*)carve((size_t)N_EDGES * 4);
  int*   bsum = (int*)carve((size_t)NB * 4);
  int*   boff = (int*)carve((size_t)NB * 4);
  u16*   Wt1 = (u16*)carve((size_t)IN_DIM * HID_DIM * 2);
  u16*   Wt2 = (u16*)carve((size_t)HID_DIM * OUT_DIM * 2);
  u16*   b1c = (u16*)carve((size_t)HID_DIM * 2);
  u16*   b2c = (u16*)carve((size_t)OUT_DIM * 2);
  u16*   xc  = (u16*)carve((size_t)N_NODES * 128 * 2);
  u16*   xa  = (u16*)carve((size_t)N_NODES * 128 * 2);
  u16*   h   = (u16*)d_out;

  detect_zero_kernel<<<391, 256, 0, stream>>>(ei, (const unsigned int*)x, flags, deg);
  prologue_kernel<<<PB_TOTAL, 256, 0, stream>>>(x, W1, b1, W2, b2, flags,
                                                deg, Wt1, Wt2, b1c, b2c, xc);
  count_kernel<<<EGRID, 256, 0, stream>>>(ei, flags, deg);
  bsum_kernel<<<NB, 1024, 0, stream>>>(deg, bsum, N_NODES);
  bscan_kernel<<<1, 64, 0, stream>>>(bsum, boff, off + N_NODES, NB);
  bfill_kernel<<<NB, 1024, 0, stream>>>(deg, boff, off, cur, dinv, N_NODES);
  fill_kernel<<<EGRID, 256, 0, stream>>>(ei, flags, cur, csr);

  agg_kernel<false, false, false>
      <<<(N_NODES * 64) / 256, 256, 0, stream>>>(xc, off, csr, dinv, nullptr, xa);
  mlp1_kernel<<<512, 256, 0, stream>>>(xa, Wt1, b1c, h);
  mlp2_kernel<<<512, 256, 0, stream>>>(h, Wt2, xa);
  agg_kernel<true, true, false>
      <<<(N_NODES * 64) / 256, 256, 0, stream>>>(xa, off, csr, dinv, b2c, d_out);
}